// Round 14
// baseline (153.930 us; speedup 1.0000x reference)
//
#include <hip/hip_runtime.h>
#include <hip/hip_fp16.h>

// MMD loss: N=4096, D=512, ns=8192. result = (1/n^2) * sum_ij sigma_i sigma_j K(L2_ij)
// bandwidth = [2*ns*sum(sq) - 2*||colsum||^2] / (ns^2-ns) / 4; scales bw*2^s, s=0..4
// K_s = exp2(c0*L2/2^s); compute e4=exp2(c0*L2/16) once, then 4 squarings.
// mmd_main: 256x256 tile, 8 waves of 128x64, 8-phase schedule (T3+T4+T5):
// per K-tile 4 phases of {ds_read subtile | stage gloads | raw barrier |
// lgkmcnt(0)+sched_barrier | setprio(1) 16xMFMA setprio(0) | raw barrier};
// boundary vmcnt(0) issued >=2 phases after last stage load (loads span barriers).

#define NS 8192
#define D_DIM 512
#define NTILE 32   // NS / 256
#define NBLK 528   // NTILE*(NTILE+1)/2 = 8*66
#define PBLK 512   // prep blocks

typedef _Float16 f16x8 __attribute__((ext_vector_type(8)));
typedef float f32x4 __attribute__((ext_vector_type(4)));

// ---------------- prep: convert + row-sq + per-block colsum/sqsum partials ----------------
__global__ __launch_bounds__(256) void prep(const float* __restrict__ src,
                                            const float* __restrict__ tgt,
                                            __half* __restrict__ Th,
                                            float* __restrict__ sq,
                                            float* __restrict__ colp,
                                            float* __restrict__ sqp) {
    __shared__ float lcs[4][D_DIM];
    __shared__ float wsq[4];
    int tid = threadIdx.x, w = tid >> 6, l = tid & 63;
    int r0 = blockIdx.x * 16 + w * 4;          // 512 blocks * 16 rows, 4 rows/wave
    float cs[8];
#pragma unroll
    for (int j = 0; j < 8; ++j) cs[j] = 0.f;
    float ws = 0.f;

#pragma unroll
    for (int rr = 0; rr < 4; ++rr) {
        int r = r0 + rr;
        const float* rowp = (r < 4096) ? (src + (size_t)r * D_DIM)
                                       : (tgt + (size_t)(r - 4096) * D_DIM);
        float4 v0 = *reinterpret_cast<const float4*>(rowp + l * 8);
        float4 v1 = *reinterpret_cast<const float4*>(rowp + l * 8 + 4);
        float f[8] = {v0.x, v0.y, v0.z, v0.w, v1.x, v1.y, v1.z, v1.w};
        __half h[8];
        float s = 0.f;
#pragma unroll
        for (int j = 0; j < 8; ++j) {
            h[j] = __float2half(f[j]);
            float fj = __half2float(h[j]);
            s += fj * fj;
            cs[j] += fj;
        }
        *reinterpret_cast<int4*>(Th + (size_t)r * D_DIM + l * 8) =
            *reinterpret_cast<const int4*>(h);
#pragma unroll
        for (int off = 32; off; off >>= 1) s += __shfl_xor(s, off, 64);
        if (l == 0) { sq[r] = s; ws += s; }
    }
    if (l == 0) wsq[w] = ws;
#pragma unroll
    for (int j = 0; j < 8; ++j) lcs[w][l * 8 + j] = cs[j];
    __syncthreads();
#pragma unroll
    for (int j = 0; j < 2; ++j) {
        int c = j * 256 + tid;                 // fully coalesced
        colp[(size_t)blockIdx.x * D_DIM + c] =
            (lcs[0][c] + lcs[1][c]) + (lcs[2][c] + lcs[3][c]);
    }
    if (tid == 0) sqp[blockIdx.x] = (wsq[0] + wsq[1]) + (wsq[2] + wsq[3]);
}

// ---------------- combine partials -> Sacc, Cacc ----------------
__global__ __launch_bounds__(512) void combine(const float* __restrict__ colp,
                                               const float* __restrict__ sqp,
                                               float* __restrict__ Sacc,
                                               float* __restrict__ Cacc) {
    __shared__ float red[512];
    __shared__ float red2[512];
    int t = threadIdx.x;                       // t = column
    float s = 0.f;
#pragma unroll 16
    for (int b = 0; b < PBLK; ++b) s += colp[(size_t)b * D_DIM + t];
    float sv = sqp[t];
    red[t] = s * s; red2[t] = sv; __syncthreads();
    for (int off = 256; off; off >>= 1) {
        if (t < off) { red[t] += red[t + off]; red2[t] += red2[t + off]; }
        __syncthreads();
    }
    if (t == 0) { Cacc[0] = red[0]; Sacc[0] = red2[0]; }
}

// ---------------- main: 256x256 tile, 8 waves of 128x64, BK=64 dbuf, 8-phase ----------------
__global__ __launch_bounds__(512, 2) void mmd_main(const __half* __restrict__ Th,
                                                   const float* __restrict__ sq,
                                                   const float* __restrict__ Sacc,
                                                   const float* __restrict__ Cacc,
                                                   float* __restrict__ partials) {
    __shared__ __half Ah[2][256 * 64];   // 32 KB each buf
    __shared__ __half Bh[2][256 * 64];
    __shared__ float wred[8];

    // XCD swizzle (528 = 8*66, bijective) then upper-triangle decode
    int borig = blockIdx.x;
    int b = (borig & 7) * (NBLK / 8) + (borig >> 3);
    int ti = 0, rem = b;
    while (rem >= NTILE - ti) { rem -= NTILE - ti; ++ti; }
    int tj = ti + rem;
    int ibase = ti * 256, jbase = tj * 256;
    float wgt = ((ti == tj) ? 1.f : 2.f) * (((ti < 16) == (tj < 16)) ? 1.f : -1.f);

    int tid = threadIdx.x;
    int wid = tid >> 6, lane = tid & 63;
    int wm = wid >> 2, wn = wid & 3;     // 2x4 wave grid; wave tile 128x64
    int cl = lane >> 4;                  // k-chunk index 0..3

    // prefetch bandwidth scalars early
    double S = (double)Sacc[0];
    double C = (double)Cacc[0];

    f32x4 acc[8][4];
#pragma unroll
    for (int m = 0; m < 8; ++m)
#pragma unroll
        for (int n = 0; n < 4; ++n) acc[m][n] = f32x4{0.f, 0.f, 0.f, 0.f};

    f16x8 afr[4], bfr[4];

    // one A-load + one B-load at stage unit 'it' of K-tile kt into buffer nbuf
    auto GLOAD2 = [&](int nbuf, int kt, int it) {
        int h16 = tid + it * 512;            // 16B unit, 2048 per matrix tile
        int row = h16 >> 3, ch = h16 & 7;
        int scol = ((ch ^ (row & 7)) * 8);   // pre-swizzled global source, LDS linear
        __builtin_amdgcn_global_load_lds(
            (const __attribute__((address_space(1))) unsigned int*)(Th + (size_t)(ibase + row) * D_DIM + kt * 64 + scol),
            (__attribute__((address_space(3))) unsigned int*)(&Ah[nbuf][h16 * 8]), 16, 0, 0);
        __builtin_amdgcn_global_load_lds(
            (const __attribute__((address_space(1))) unsigned int*)(Th + (size_t)(jbase + row) * D_DIM + kt * 64 + scol),
            (__attribute__((address_space(3))) unsigned int*)(&Bh[nbuf][h16 * 8]), 16, 0, 0);
    };
    auto LOADB = [&](int buf, int ks) {
#pragma unroll
        for (int n = 0; n < 4; ++n) {
            int rb = wn * 64 + n * 16 + (lane & 15);
            int pc = (ks * 4 + cl) ^ (rb & 7);
            bfr[n] = *reinterpret_cast<const f16x8*>(&Bh[buf][rb * 64 + pc * 8]);
        }
    };
    auto LOADA = [&](int buf, int ks, int half) {
#pragma unroll
        for (int m = 0; m < 4; ++m) {
            int ra = wm * 128 + (half * 4 + m) * 16 + (lane & 15);
            int pc = (ks * 4 + cl) ^ (ra & 7);
            afr[m] = *reinterpret_cast<const f16x8*>(&Ah[buf][ra * 64 + pc * 8]);
        }
    };
    auto DOMFMA = [&](int half) {
#pragma unroll
        for (int m = 0; m < 4; ++m)
#pragma unroll
            for (int n = 0; n < 4; ++n)
                acc[half * 4 + m][n] =
                    __builtin_amdgcn_mfma_f32_16x16x32_f16(afr[m], bfr[n], acc[half * 4 + m][n], 0, 0, 0);
    };

    // prologue: stage K-tile 0 fully, drain, align
#pragma unroll
    for (int it = 0; it < 4; ++it) GLOAD2(0, 0, it);
    asm volatile("s_waitcnt vmcnt(0)" ::: "memory");
    __builtin_amdgcn_s_barrier();
    __builtin_amdgcn_sched_barrier(0);

#pragma unroll
    for (int t = 0; t < 8; ++t) {
        int buf = t & 1, nbuf = buf ^ 1;
        // ---- phase 0: ks=0, m-half 0; stage units 0,1 of t+1 ----
        LOADB(buf, 0);
        LOADA(buf, 0, 0);
        if (t < 7) { GLOAD2(nbuf, t + 1, 0); GLOAD2(nbuf, t + 1, 1); }
        __builtin_amdgcn_s_barrier();
        asm volatile("s_waitcnt lgkmcnt(0)" ::: "memory");
        __builtin_amdgcn_sched_barrier(0);
        __builtin_amdgcn_s_setprio(1);
        DOMFMA(0);
        __builtin_amdgcn_s_setprio(0);
        __builtin_amdgcn_s_barrier();
        __builtin_amdgcn_sched_barrier(0);
        // ---- phase 1: ks=0, m-half 1; stage units 2,3 of t+1 ----
        LOADA(buf, 0, 1);
        if (t < 7) { GLOAD2(nbuf, t + 1, 2); GLOAD2(nbuf, t + 1, 3); }
        __builtin_amdgcn_s_barrier();
        asm volatile("s_waitcnt lgkmcnt(0)" ::: "memory");
        __builtin_amdgcn_sched_barrier(0);
        __builtin_amdgcn_s_setprio(1);
        DOMFMA(1);
        __builtin_amdgcn_s_setprio(0);
        __builtin_amdgcn_s_barrier();
        __builtin_amdgcn_sched_barrier(0);
        // ---- phase 2: ks=1, m-half 0 ----
        LOADB(buf, 1);
        LOADA(buf, 1, 0);
        __builtin_amdgcn_s_barrier();
        asm volatile("s_waitcnt lgkmcnt(0)" ::: "memory");
        __builtin_amdgcn_sched_barrier(0);
        __builtin_amdgcn_s_setprio(1);
        DOMFMA(0);
        __builtin_amdgcn_s_setprio(0);
        __builtin_amdgcn_s_barrier();
        __builtin_amdgcn_sched_barrier(0);
        // ---- phase 3: ks=1, m-half 1; then K-tile boundary ----
        LOADA(buf, 1, 1);
        __builtin_amdgcn_s_barrier();
        asm volatile("s_waitcnt lgkmcnt(0)" ::: "memory");
        __builtin_amdgcn_sched_barrier(0);
        __builtin_amdgcn_s_setprio(1);
        DOMFMA(1);
        __builtin_amdgcn_s_setprio(0);
        // boundary: my t+1 loads landed (issued >=2 phases ago), then all waves
        if (t < 7) asm volatile("s_waitcnt vmcnt(0)" ::: "memory");
        __builtin_amdgcn_s_barrier();
        __builtin_amdgcn_sched_barrier(0);
    }

    // ---- bandwidth scalar; fold /16 for the square-chain ----
    double sumL2 = 2.0 * (double)NS * S - 2.0 * C;
    double bwv = sumL2 / ((double)NS * NS - (double)NS) / 4.0;  // / kernel_mul^(num//2)
    float c0s = (float)(-1.4426950408889634 / (bwv * 16.0));    // c0/16
    float m2c0s = -2.f * c0s;

    // ---- epilogue: x4 = (c0/16)*L2 ; e4=exp2(x4); square up; signed sum ----
    float sci[32], scj[4];
#pragma unroll
    for (int m = 0; m < 8; ++m)
#pragma unroll
        for (int r = 0; r < 4; ++r)
            sci[m * 4 + r] = sq[ibase + wm * 128 + m * 16 + (lane >> 4) * 4 + r] * c0s;
#pragma unroll
    for (int n = 0; n < 4; ++n)
        scj[n] = sq[jbase + wn * 64 + n * 16 + (lane & 15)] * c0s;

    float ksum = 0.f;
#pragma unroll
    for (int m = 0; m < 8; ++m)
#pragma unroll
        for (int n = 0; n < 4; ++n)
#pragma unroll
            for (int r = 0; r < 4; ++r) {
                float x4 = fmaf(acc[m][n][r], m2c0s, sci[m * 4 + r] + scj[n]);
                float e4 = __builtin_amdgcn_exp2f(x4);   // exp2(c0*L2/16)
                float e3 = e4 * e4;
                float e2 = e3 * e3;
                float e1 = e2 * e2;
                float e0 = e1 * e1;                      // exp2(c0*L2)
                ksum += ((e4 + e3) + (e2 + e1)) + e0;
            }
#pragma unroll
    for (int off = 32; off; off >>= 1) ksum += __shfl_xor(ksum, off, 64);
    if (lane == 0) wred[wid] = ksum;
    __syncthreads();
    if (tid == 0) {
        float tot = ((wred[0] + wred[1]) + (wred[2] + wred[3]))
                  + ((wred[4] + wred[5]) + (wred[6] + wred[7]));
        partials[borig] = tot * wgt;
    }
}

__global__ void finalize(const float* __restrict__ partials, float* __restrict__ out) {
    __shared__ double red[256];
    int t = threadIdx.x;
    double s = 0.0;
    for (int i = t; i < NBLK; i += 256) s += (double)partials[i];
    red[t] = s; __syncthreads();
    for (int off = 128; off; off >>= 1) { if (t < off) red[t] += red[t + off]; __syncthreads(); }
    if (t == 0) out[0] = (float)(red[0] * (1.0 / (4096.0 * 4096.0)));
}

extern "C" void kernel_launch(void* const* d_in, const int* in_sizes, int n_in,
                              void* d_out, int out_size, void* d_ws, size_t ws_size,
                              hipStream_t stream) {
    (void)in_sizes; (void)n_in; (void)out_size; (void)ws_size;
    const float* src = (const float*)d_in[0];
    const float* tgt = (const float*)d_in[1];
    char* ws = (char*)d_ws;
    __half* Th      = (__half*)ws;                     // 8,388,608 B
    float* sq       = (float*)(ws + 8388608);          // 32 KB            -> 8421376
    float* colp     = (float*)(ws + 8421376);          // 512*512*4 = 1 MB -> 9469952
    float* sqp      = (float*)(ws + 9469952);          // 2 KB             -> 9472000
    float* Sacc     = (float*)(ws + 9472000);          // 4 B
    float* Cacc     = (float*)(ws + 9472004);          // 4 B
    float* partials = (float*)(ws + 9472008);          // 528*4 B
    float* out      = (float*)d_out;

    hipLaunchKernelGGL(prep, dim3(PBLK), dim3(256), 0, stream, src, tgt, Th, sq, colp, sqp);
    hipLaunchKernelGGL(combine, dim3(1), dim3(512), 0, stream, colp, sqp, Sacc, Cacc);
    hipLaunchKernelGGL(mmd_main, dim3(NBLK), dim3(512), 0, stream, Th, sq, Sacc, Cacc, partials);
    hipLaunchKernelGGL(finalize, dim3(1), dim3(256), 0, stream, partials, out);
}

// Round 15
// 140.788 us; speedup vs baseline: 1.0933x; 1.0933x over previous
//
#include <hip/hip_runtime.h>
#include <hip/hip_fp16.h>

// MMD loss: N=4096, D=512, ns=8192. result = (1/n^2) * sum_ij sigma_i sigma_j K(L2_ij)
// bandwidth = [2*ns*sum(sq) - 2*||colsum||^2] / (ns^2-ns) / 4; scales bw*2^s, s=0..4
// K_s = exp2(c0*L2/2^s); e4=exp2(c0*L2/16) once, then 4 squarings.
// mmd_main: PERSISTENT 256 blocks + atomic ticket over 528 tiles (fixes the
// 3-round tail: 528/256 rounds up to 3, last round 16/256 CUs busy).
// Proven R11 2-phase tile body (256x256, 8 waves of 128x64, BK=64 dbuf).
// Bandwidth reduce fused into mmd_main prologue (16 KB colsumR, deterministic).

#define NS 8192
#define D_DIM 512
#define NTILE 32   // NS / 256
#define NBLK 528   // NTILE*(NTILE+1)/2 = 8*66
#define PBLK 512   // prep blocks
#define NREP 8     // colsum replicas

typedef _Float16 f16x8 __attribute__((ext_vector_type(8)));
typedef float f32x4 __attribute__((ext_vector_type(4)));

// ---------------- prep: convert + row-sq + replicated colsum + sum(sq) ----------------
__global__ __launch_bounds__(256) void prep(const float* __restrict__ src,
                                            const float* __restrict__ tgt,
                                            __half* __restrict__ Th,
                                            float* __restrict__ sq,
                                            float* __restrict__ colsumR,
                                            float* __restrict__ Sacc) {
    __shared__ float lcs[4][D_DIM];
    __shared__ float wsq[4];
    int tid = threadIdx.x, w = tid >> 6, l = tid & 63;
    int r0 = blockIdx.x * 16 + w * 4;          // 512 blocks * 16 rows, 4 rows/wave
    float cs[8];
#pragma unroll
    for (int j = 0; j < 8; ++j) cs[j] = 0.f;
    float ws = 0.f;

#pragma unroll
    for (int rr = 0; rr < 4; ++rr) {
        int r = r0 + rr;
        const float* rowp = (r < 4096) ? (src + (size_t)r * D_DIM)
                                       : (tgt + (size_t)(r - 4096) * D_DIM);
        float4 v0 = *reinterpret_cast<const float4*>(rowp + l * 8);
        float4 v1 = *reinterpret_cast<const float4*>(rowp + l * 8 + 4);
        float f[8] = {v0.x, v0.y, v0.z, v0.w, v1.x, v1.y, v1.z, v1.w};
        __half h[8];
        float s = 0.f;
#pragma unroll
        for (int j = 0; j < 8; ++j) {
            h[j] = __float2half(f[j]);
            float fj = __half2float(h[j]);
            s += fj * fj;
            cs[j] += fj;
        }
        *reinterpret_cast<int4*>(Th + (size_t)r * D_DIM + l * 8) =
            *reinterpret_cast<const int4*>(h);
#pragma unroll
        for (int off = 32; off; off >>= 1) s += __shfl_xor(s, off, 64);
        if (l == 0) { sq[r] = s; ws += s; }
    }
    if (l == 0) wsq[w] = ws;
#pragma unroll
    for (int j = 0; j < 8; ++j) lcs[w][l * 8 + j] = cs[j];
    __syncthreads();
    float* myrep = colsumR + (blockIdx.x & (NREP - 1)) * D_DIM;
#pragma unroll
    for (int j = 0; j < 2; ++j) {
        int c = j * 256 + tid;
        float v = (lcs[0][c] + lcs[1][c]) + (lcs[2][c] + lcs[3][c]);
        atomicAdd(&myrep[c], v);
    }
    if (tid == 0) atomicAdd(Sacc, (wsq[0] + wsq[1]) + (wsq[2] + wsq[3]));
}

// ---------------- main: persistent blocks, ticket loop over 528 tiles ----------------
__global__ __launch_bounds__(512, 2) void mmd_main(const __half* __restrict__ Th,
                                                   const float* __restrict__ sq,
                                                   const float* __restrict__ colsumR,
                                                   const float* __restrict__ Sacc,
                                                   unsigned int* __restrict__ ticket,
                                                   float* __restrict__ partials) {
    __shared__ __half Ah[2][256 * 64];   // 32 KB each buf
    __shared__ __half Bh[2][256 * 64];
    __shared__ float wred[8];
    __shared__ int tIdx;

    int tid = threadIdx.x;
    int wid = tid >> 6, lane = tid & 63;
    int wm = wid >> 2, wn = wid & 3;     // 2x4 wave grid; wave tile 128x64
    int cl = lane >> 4;                  // k-chunk index 0..3

    // ---- fused bandwidth reduce (deterministic, identical in every block) ----
    float colv = 0.f;
#pragma unroll
    for (int r = 0; r < NREP; ++r) colv += colsumR[r * D_DIM + tid];  // tid = column
    float c2 = colv * colv;
#pragma unroll
    for (int off = 32; off; off >>= 1) c2 += __shfl_xor(c2, off, 64);
    if (lane == 0) wred[wid] = c2;
    __syncthreads();
    float Cf = ((wred[0] + wred[1]) + (wred[2] + wred[3]))
             + ((wred[4] + wred[5]) + (wred[6] + wred[7]));
    double S = (double)Sacc[0];
    double sumL2 = 2.0 * (double)NS * S - 2.0 * (double)Cf;
    double bwv = sumL2 / ((double)NS * NS - (double)NS) / 4.0;  // / kernel_mul^(num//2)
    float c0s = (float)(-1.4426950408889634 / (bwv * 16.0));    // c0/16
    float m2c0s = -2.f * c0s;

    auto STAGE = [&](int buf, int ibase, int jbase, int k0) {
#pragma unroll
        for (int it = 0; it < 4; ++it) {
            int h16 = tid + it * 512;            // 16B unit, 2048 per matrix tile
            int row = h16 >> 3, ch = h16 & 7;
            int scol = ((ch ^ (row & 7)) * 8);   // pre-swizzled source, LDS linear
            __builtin_amdgcn_global_load_lds(
                (const __attribute__((address_space(1))) unsigned int*)(Th + (size_t)(ibase + row) * D_DIM + k0 + scol),
                (__attribute__((address_space(3))) unsigned int*)(&Ah[buf][h16 * 8]), 16, 0, 0);
            __builtin_amdgcn_global_load_lds(
                (const __attribute__((address_space(1))) unsigned int*)(Th + (size_t)(jbase + row) * D_DIM + k0 + scol),
                (__attribute__((address_space(3))) unsigned int*)(&Bh[buf][h16 * 8]), 16, 0, 0);
        }
    };

    // ---- persistent ticket loop ----
    for (;;) {
        __syncthreads();                 // wred/tIdx reuse + prev-iter LDS reads done
        if (tid == 0) tIdx = (int)atomicAdd(ticket, 1u);
        __syncthreads();
        int tt = tIdx;
        if (tt >= NBLK) break;

        // upper-triangle decode
        int ti = 0, rem = tt;
        while (rem >= NTILE - ti) { rem -= NTILE - ti; ++ti; }
        int tj = ti + rem;
        int ibase = ti * 256, jbase = tj * 256;
        float wgt = ((ti == tj) ? 1.f : 2.f) * (((ti < 16) == (tj < 16)) ? 1.f : -1.f);

        f32x4 acc[8][4];
#pragma unroll
        for (int m = 0; m < 8; ++m)
#pragma unroll
            for (int n = 0; n < 4; ++n) acc[m][n] = f32x4{0.f, 0.f, 0.f, 0.f};

        auto COMPUTE = [&](int buf) {
#pragma unroll
            for (int ks = 0; ks < 2; ++ks) {
                f16x8 afr[8], bfr[4];
#pragma unroll
                for (int m = 0; m < 8; ++m) {
                    int ra = wm * 128 + m * 16 + (lane & 15);
                    int pc = (ks * 4 + cl) ^ (ra & 7);
                    afr[m] = *reinterpret_cast<const f16x8*>(&Ah[buf][ra * 64 + pc * 8]);
                }
#pragma unroll
                for (int n = 0; n < 4; ++n) {
                    int rb = wn * 64 + n * 16 + (lane & 15);
                    int pc = (ks * 4 + cl) ^ (rb & 7);
                    bfr[n] = *reinterpret_cast<const f16x8*>(&Bh[buf][rb * 64 + pc * 8]);
                }
#pragma unroll
                for (int m = 0; m < 8; ++m)
#pragma unroll
                    for (int n = 0; n < 4; ++n)
                        acc[m][n] = __builtin_amdgcn_mfma_f32_16x16x32_f16(afr[m], bfr[n], acc[m][n], 0, 0, 0);
            }
        };

        // proven 2-phase pipeline: stage next BEFORE compute; one barrier/tile
        STAGE(0, ibase, jbase, 0);
        __syncthreads();
        int buf = 0;
#pragma unroll
        for (int t = 0; t < 7; ++t) {
            STAGE(buf ^ 1, ibase, jbase, (t + 1) * 64);
            COMPUTE(buf);
            __syncthreads();
            buf ^= 1;
        }
        COMPUTE(buf);

        // ---- epilogue: x4=(c0/16)*L2; e4=exp2(x4); square up; signed sum ----
        float sci[32], scj[4];
#pragma unroll
        for (int m = 0; m < 8; ++m)
#pragma unroll
            for (int r = 0; r < 4; ++r)
                sci[m * 4 + r] = sq[ibase + wm * 128 + m * 16 + (lane >> 4) * 4 + r] * c0s;
#pragma unroll
        for (int n = 0; n < 4; ++n)
            scj[n] = sq[jbase + wn * 64 + n * 16 + (lane & 15)] * c0s;

        float ksum = 0.f;
#pragma unroll
        for (int m = 0; m < 8; ++m)
#pragma unroll
            for (int n = 0; n < 4; ++n)
#pragma unroll
                for (int r = 0; r < 4; ++r) {
                    float x4 = fmaf(acc[m][n][r], m2c0s, sci[m * 4 + r] + scj[n]);
                    float e4 = __builtin_amdgcn_exp2f(x4);   // exp2(c0*L2/16)
                    float e3 = e4 * e4;
                    float e2 = e3 * e3;
                    float e1 = e2 * e2;
                    float e0 = e1 * e1;                      // exp2(c0*L2)
                    ksum += ((e4 + e3) + (e2 + e1)) + e0;
                }
#pragma unroll
        for (int off = 32; off; off >>= 1) ksum += __shfl_xor(ksum, off, 64);
        if (lane == 0) wred[wid] = ksum;
        __syncthreads();
        if (tid == 0) {
            float tot = ((wred[0] + wred[1]) + (wred[2] + wred[3]))
                      + ((wred[4] + wred[5]) + (wred[6] + wred[7]));
            partials[tt] = tot * wgt;
        }
    }
}

__global__ void finalize(const float* __restrict__ partials, float* __restrict__ out) {
    __shared__ double red[256];
    int t = threadIdx.x;
    double s = 0.0;
    for (int i = t; i < NBLK; i += 256) s += (double)partials[i];
    red[t] = s; __syncthreads();
    for (int off = 128; off; off >>= 1) { if (t < off) red[t] += red[t + off]; __syncthreads(); }
    if (t == 0) out[0] = (float)(red[0] * (1.0 / (4096.0 * 4096.0)));
}

extern "C" void kernel_launch(void* const* d_in, const int* in_sizes, int n_in,
                              void* d_out, int out_size, void* d_ws, size_t ws_size,
                              hipStream_t stream) {
    (void)in_sizes; (void)n_in; (void)out_size; (void)ws_size;
    const float* src = (const float*)d_in[0];
    const float* tgt = (const float*)d_in[1];
    char* ws = (char*)d_ws;
    __half* Th        = (__half*)ws;                   // 8,388,608 B
    float* sq         = (float*)(ws + 8388608);        // 32 KB        -> 8421376
    float* colsumR    = (float*)(ws + 8421376);        // 8*512*4=16 KB-> 8437760
    float* Sacc       = (float*)(ws + 8437760);        // 4 B
    unsigned int* ticket = (unsigned int*)(ws + 8437764); // 4 B
    float* partials   = (float*)(ws + 8437768);        // 528*4 B
    float* out        = (float*)d_out;

    hipMemsetAsync(colsumR, 0, 16384 + 8, stream);     // colsumR + Sacc + ticket
    hipLaunchKernelGGL(prep, dim3(PBLK), dim3(256), 0, stream, src, tgt, Th, sq, colsumR, Sacc);
    hipLaunchKernelGGL(mmd_main, dim3(256), dim3(512), 0, stream, Th, sq, colsumR, Sacc, ticket, partials);
    hipLaunchKernelGGL(finalize, dim3(1), dim3(256), 0, stream, partials, out);
}

// Round 16
// 136.644 us; speedup vs baseline: 1.1265x; 1.0303x over previous
//
#include <hip/hip_runtime.h>
#include <hip/hip_fp16.h>

// MMD loss: N=4096, D=512, ns=8192. result = (1/n^2) * sum_ij sigma_i sigma_j K(L2_ij)
// bandwidth = [2*ns*sum(sq) - 2*||colsum||^2] / (ns^2-ns) / 4; scales bw*2^s, s=0..4
// K_s = exp2(c0*L2/2^s); e4=exp2(c0*L2/16) once, then 4 squarings.
// mmd_main: static grid 528 (R11-proven, no spill), 256x256 tile, 8 waves of
// 128x64, BK=64 dbuf 2-phase; bandwidth reduce fused into prologue (no combine).

#define NS 8192
#define D_DIM 512
#define NTILE 32   // NS / 256
#define NBLK 528   // NTILE*(NTILE+1)/2 = 8*66
#define PBLK 512   // prep blocks
#define NREP 8     // colsum replicas

typedef _Float16 f16x8 __attribute__((ext_vector_type(8)));
typedef float f32x4 __attribute__((ext_vector_type(4)));

// ---------------- prep: convert + row-sq + replicated colsum + sum(sq) ----------------
__global__ __launch_bounds__(256) void prep(const float* __restrict__ src,
                                            const float* __restrict__ tgt,
                                            __half* __restrict__ Th,
                                            float* __restrict__ sq,
                                            float* __restrict__ colsumR,
                                            float* __restrict__ Sacc) {
    __shared__ float lcs[4][D_DIM];
    __shared__ float wsq[4];
    int tid = threadIdx.x, w = tid >> 6, l = tid & 63;
    int r0 = blockIdx.x * 16 + w * 4;          // 512 blocks * 16 rows, 4 rows/wave
    float cs[8];
#pragma unroll
    for (int j = 0; j < 8; ++j) cs[j] = 0.f;
    float ws = 0.f;

#pragma unroll
    for (int rr = 0; rr < 4; ++rr) {
        int r = r0 + rr;
        const float* rowp = (r < 4096) ? (src + (size_t)r * D_DIM)
                                       : (tgt + (size_t)(r - 4096) * D_DIM);
        float4 v0 = *reinterpret_cast<const float4*>(rowp + l * 8);
        float4 v1 = *reinterpret_cast<const float4*>(rowp + l * 8 + 4);
        float f[8] = {v0.x, v0.y, v0.z, v0.w, v1.x, v1.y, v1.z, v1.w};
        __half h[8];
        float s = 0.f;
#pragma unroll
        for (int j = 0; j < 8; ++j) {
            h[j] = __float2half(f[j]);
            float fj = __half2float(h[j]);
            s += fj * fj;
            cs[j] += fj;
        }
        *reinterpret_cast<int4*>(Th + (size_t)r * D_DIM + l * 8) =
            *reinterpret_cast<const int4*>(h);
#pragma unroll
        for (int off = 32; off; off >>= 1) s += __shfl_xor(s, off, 64);
        if (l == 0) { sq[r] = s; ws += s; }
    }
    if (l == 0) wsq[w] = ws;
#pragma unroll
    for (int j = 0; j < 8; ++j) lcs[w][l * 8 + j] = cs[j];
    __syncthreads();
    float* myrep = colsumR + (blockIdx.x & (NREP - 1)) * D_DIM;
#pragma unroll
    for (int j = 0; j < 2; ++j) {
        int c = j * 256 + tid;
        float v = (lcs[0][c] + lcs[1][c]) + (lcs[2][c] + lcs[3][c]);
        atomicAdd(&myrep[c], v);
    }
    if (tid == 0) atomicAdd(Sacc, (wsq[0] + wsq[1]) + (wsq[2] + wsq[3]));
}

// ---------------- main: static grid 528, fused bw prologue, 2-phase pipeline ----------------
__global__ __launch_bounds__(512, 2) void mmd_main(const __half* __restrict__ Th,
                                                   const float* __restrict__ sq,
                                                   const float* __restrict__ colsumR,
                                                   const float* __restrict__ Sacc,
                                                   float* __restrict__ partials) {
    __shared__ __half Ah[2][256 * 64];   // 32 KB each buf
    __shared__ __half Bh[2][256 * 64];
    __shared__ float wred[8];

    // XCD swizzle (528 = 8*66, bijective) then upper-triangle decode
    int borig = blockIdx.x;
    int b = (borig & 7) * (NBLK / 8) + (borig >> 3);
    int ti = 0, rem = b;
    while (rem >= NTILE - ti) { rem -= NTILE - ti; ++ti; }
    int tj = ti + rem;
    int ibase = ti * 256, jbase = tj * 256;
    float wgt = ((ti == tj) ? 1.f : 2.f) * (((ti < 16) == (tj < 16)) ? 1.f : -1.f);

    int tid = threadIdx.x;
    int wid = tid >> 6, lane = tid & 63;
    int wm = wid >> 2, wn = wid & 3;     // 2x4 wave grid; wave tile 128x64
    int cl = lane >> 4;                  // k-chunk index 0..3

    // ---- fused bandwidth reduce (deterministic, identical in every block) ----
    float colv = 0.f;
#pragma unroll
    for (int r = 0; r < NREP; ++r) colv += colsumR[r * D_DIM + tid];  // tid = column
    float c2 = colv * colv;
#pragma unroll
    for (int off = 32; off; off >>= 1) c2 += __shfl_xor(c2, off, 64);
    if (lane == 0) wred[wid] = c2;
    __syncthreads();
    float Cf = ((wred[0] + wred[1]) + (wred[2] + wred[3]))
             + ((wred[4] + wred[5]) + (wred[6] + wred[7]));
    double S = (double)Sacc[0];
    double sumL2 = 2.0 * (double)NS * S - 2.0 * (double)Cf;
    double bwv = sumL2 / ((double)NS * NS - (double)NS) / 4.0;  // / kernel_mul^(num//2)
    float c0s = (float)(-1.4426950408889634 / (bwv * 16.0));    // c0/16
    float m2c0s = -2.f * c0s;
    __syncthreads();                    // wred reuse safety

    f32x4 acc[8][4];
#pragma unroll
    for (int m = 0; m < 8; ++m)
#pragma unroll
        for (int n = 0; n < 4; ++n) acc[m][n] = f32x4{0.f, 0.f, 0.f, 0.f};

    // stage 256x64 tiles (global source pre-swizzled chunk^(row&7), LDS linear)
    auto STAGE = [&](int buf, int k0) {
#pragma unroll
        for (int it = 0; it < 4; ++it) {
            int h16 = tid + it * 512;            // 16B unit, 2048 per tile
            int row = h16 >> 3, ch = h16 & 7;
            int scol = ((ch ^ (row & 7)) * 8);
            __builtin_amdgcn_global_load_lds(
                (const __attribute__((address_space(1))) unsigned int*)(Th + (size_t)(ibase + row) * D_DIM + k0 + scol),
                (__attribute__((address_space(3))) unsigned int*)(&Ah[buf][h16 * 8]), 16, 0, 0);
            __builtin_amdgcn_global_load_lds(
                (const __attribute__((address_space(1))) unsigned int*)(Th + (size_t)(jbase + row) * D_DIM + k0 + scol),
                (__attribute__((address_space(3))) unsigned int*)(&Bh[buf][h16 * 8]), 16, 0, 0);
        }
    };

    auto COMPUTE = [&](int buf) {
#pragma unroll
        for (int ks = 0; ks < 2; ++ks) {
            f16x8 afr[8], bfr[4];
#pragma unroll
            for (int m = 0; m < 8; ++m) {
                int ra = wm * 128 + m * 16 + (lane & 15);
                int pc = (ks * 4 + cl) ^ (ra & 7);
                afr[m] = *reinterpret_cast<const f16x8*>(&Ah[buf][ra * 64 + pc * 8]);
            }
#pragma unroll
            for (int n = 0; n < 4; ++n) {
                int rb = wn * 64 + n * 16 + (lane & 15);
                int pc = (ks * 4 + cl) ^ (rb & 7);
                bfr[n] = *reinterpret_cast<const f16x8*>(&Bh[buf][rb * 64 + pc * 8]);
            }
#pragma unroll
            for (int m = 0; m < 8; ++m)
#pragma unroll
                for (int n = 0; n < 4; ++n)
                    acc[m][n] = __builtin_amdgcn_mfma_f32_16x16x32_f16(afr[m], bfr[n], acc[m][n], 0, 0, 0);
        }
    };

    // proven 2-phase pipeline: stage next BEFORE compute; one barrier per tile
    STAGE(0, 0);
    __syncthreads();
    int buf = 0;
#pragma unroll
    for (int t = 0; t < 7; ++t) {
        STAGE(buf ^ 1, (t + 1) * 64);
        COMPUTE(buf);
        __syncthreads();
        buf ^= 1;
    }
    COMPUTE(buf);

    // ---- epilogue: x4=(c0/16)*L2; e4=exp2(x4); square up; signed sum ----
    float sci[32], scj[4];
#pragma unroll
    for (int m = 0; m < 8; ++m)
#pragma unroll
        for (int r = 0; r < 4; ++r)
            sci[m * 4 + r] = sq[ibase + wm * 128 + m * 16 + (lane >> 4) * 4 + r] * c0s;
#pragma unroll
    for (int n = 0; n < 4; ++n)
        scj[n] = sq[jbase + wn * 64 + n * 16 + (lane & 15)] * c0s;

    float ksum = 0.f;
#pragma unroll
    for (int m = 0; m < 8; ++m)
#pragma unroll
        for (int n = 0; n < 4; ++n)
#pragma unroll
            for (int r = 0; r < 4; ++r) {
                float x4 = fmaf(acc[m][n][r], m2c0s, sci[m * 4 + r] + scj[n]);
                float e4 = __builtin_amdgcn_exp2f(x4);   // exp2(c0*L2/16)
                float e3 = e4 * e4;
                float e2 = e3 * e3;
                float e1 = e2 * e2;
                float e0 = e1 * e1;                      // exp2(c0*L2)
                ksum += ((e4 + e3) + (e2 + e1)) + e0;
            }
#pragma unroll
    for (int off = 32; off; off >>= 1) ksum += __shfl_xor(ksum, off, 64);
    if (lane == 0) wred[wid] = ksum;
    __syncthreads();
    if (tid == 0) {
        float tot = ((wred[0] + wred[1]) + (wred[2] + wred[3]))
                  + ((wred[4] + wred[5]) + (wred[6] + wred[7]));
        partials[borig] = tot * wgt;
    }
}

__global__ void finalize(const float* __restrict__ partials, float* __restrict__ out) {
    __shared__ double red[256];
    int t = threadIdx.x;
    double s = 0.0;
    for (int i = t; i < NBLK; i += 256) s += (double)partials[i];
    red[t] = s; __syncthreads();
    for (int off = 128; off; off >>= 1) { if (t < off) red[t] += red[t + off]; __syncthreads(); }
    if (t == 0) out[0] = (float)(red[0] * (1.0 / (4096.0 * 4096.0)));
}

extern "C" void kernel_launch(void* const* d_in, const int* in_sizes, int n_in,
                              void* d_out, int out_size, void* d_ws, size_t ws_size,
                              hipStream_t stream) {
    (void)in_sizes; (void)n_in; (void)out_size; (void)ws_size;
    const float* src = (const float*)d_in[0];
    const float* tgt = (const float*)d_in[1];
    char* ws = (char*)d_ws;
    __half* Th      = (__half*)ws;                     // 8,388,608 B
    float* sq       = (float*)(ws + 8388608);          // 32 KB        -> 8421376
    float* colsumR  = (float*)(ws + 8421376);          // 8*512*4=16 KB-> 8437760
    float* Sacc     = (float*)(ws + 8437760);          // 4 B
    float* partials = (float*)(ws + 8437764);          // 528*4 B
    float* out      = (float*)d_out;

    hipMemsetAsync(colsumR, 0, 16384 + 4, stream);     // colsumR + Sacc
    hipLaunchKernelGGL(prep, dim3(PBLK), dim3(256), 0, stream, src, tgt, Th, sq, colsumR, Sacc);
    hipLaunchKernelGGL(mmd_main, dim3(NBLK), dim3(512), 0, stream, Th, sq, colsumR, Sacc, partials);
    hipLaunchKernelGGL(finalize, dim3(1), dim3(256), 0, stream, partials, out);
}